// Round 5
// baseline (279.354 us; speedup 1.0000x reference)
//
#include <hip/hip_runtime.h>
#include <hip/hip_bf16.h>
#include <math.h>

#define B_ 2
#define S_ 1024
#define H_ 768
#define D_ 24
#define HID_ 96
#define OH_ 768
#define VI_ 2304

typedef short bf16x8 __attribute__((ext_vector_type(8)));
typedef float f32x4 __attribute__((ext_vector_type(4)));
typedef float f32x2 __attribute__((ext_vector_type(2)));
typedef unsigned short u16;

static __device__ __forceinline__ float relu_(float x) { return x > 0.f ? x : 0.f; }

static __device__ __forceinline__ short f2bf(float f) {
    __hip_bfloat16 h = __float2bfloat16(f);
    return *reinterpret_cast<short*>(&h);
}
static __device__ __forceinline__ float bf2f(short s) {
    unsigned u = ((unsigned)(u16)s) << 16;
    return __uint_as_float(u);
}
// packed f32->bf16 converts (1 instr / 2 values), RNE on gfx950
static __device__ __forceinline__ unsigned cvtpk(float a, float b) {
    unsigned d;
    asm("v_cvt_pk_bf16_f32 %0, %1, %2" : "=v"(d) : "v"(a), "v"(b));
    return d;
}
static __device__ __forceinline__ unsigned cvtpk_abs(float a, float b) {
    unsigned d;
    asm("v_cvt_pk_bf16_f32 %0, |%1|, |%2|" : "=v"(d) : "v"(a), "v"(b));
    return d;
}

static __device__ __forceinline__ void gl_lds16(const void* g, void* l) {
    __builtin_amdgcn_global_load_lds(
        (const __attribute__((address_space(1))) unsigned int*)g,
        (__attribute__((address_space(3))) unsigned int*)l, 16, 0, 0);
}

#define NEGF (-3.402823466e38f)

// ---------------------------------------------------------------------------
// K1: per-token projections Zj, Zi  [B,S,D]
// ---------------------------------------------------------------------------
__global__ __launch_bounds__(256) void proj_kernel(
    const float* __restrict__ Hj, const float* __restrict__ Hi,
    const float* __restrict__ Wpj, const float* __restrict__ Wpi,
    float* __restrict__ Zj, float* __restrict__ Zi)
{
    __shared__ float rowj[H_], rowi[H_];
    const int t = blockIdx.x;           // 0..B*S-1
    const int tid = threadIdx.x;
    const float* hj = Hj + (size_t)t * H_;
    const float* hi = Hi + (size_t)t * H_;
    for (int x = tid; x < H_; x += 256) { rowj[x] = hj[x]; rowi[x] = hi[x]; }
    __syncthreads();

    const int g = tid & 7;              // 8 threads per output
    for (int o = tid >> 3; o < 2 * D_; o += 32) {
        const float* row;
        const float* w;
        if (o < D_) { row = rowj; w = Wpj + o * H_; }
        else        { row = rowi; w = Wpi + (o - D_) * H_; }
        float s = 0.f;
        #pragma unroll 8
        for (int c = 0; c < H_ / 8; ++c) s += row[g + 8 * c] * w[g + 8 * c];
        s += __shfl_down(s, 4, 8);
        s += __shfl_down(s, 2, 8);
        s += __shfl_down(s, 1, 8);
        if (g == 0) {
            if (o < D_) Zj[(size_t)t * D_ + o] = s;
            else        Zi[(size_t)t * D_ + (o - D_)] = s;
        }
    }
}

// ---------------------------------------------------------------------------
// K2: pair logits via MFMA, divergence-free, cvt_pk builds, packed epilogue.
// Feature K-steps: s0=[Zi|0*8], s1=[Zj*Zi|0*8], s2=[|Zj-Zi||0*8]; Zj-linear
// + bias folded into Aterm (fp32), consumed as MFMA C-in via LDS b128 reads.
// mfma(W, F, acc): D row=k, col=pair.
// ---------------------------------------------------------------------------
__global__ __launch_bounds__(256) void pair_mfma_kernel(
    const float* __restrict__ Zj, const float* __restrict__ Zi,
    const float* __restrict__ Ws1, const float* __restrict__ Ws2,
    const float* __restrict__ bs1, const float* __restrict__ bs2,
    float* __restrict__ P)
{
    __shared__ float sZj32[16 * 32];    // plain, cols 24..31 = 0
    __shared__ float sZi32[64 * 32];    // granule(4f) at d^(row&7)
    __shared__ u16   sZi16[64 * 64];    // granule(8h) at c^(row&7), c<4
    __shared__ float sAterm[16 * 96];   // [j][k]
    __shared__ float sW2[96];

    const int j0 = blockIdx.x * 16, i0 = blockIdx.y * 64, b = blockIdx.z;
    const int tid = threadIdx.x;
    const int lane = tid & 63;
    const int wv = tid >> 6;
    const int q = lane & 15, g = lane >> 4;

    // ---- stage tiles ----
    if (tid < 128) {                    // zj32: 16 rows x 8 granules
        int r = tid >> 3, d = tid & 7;
        float4 v = make_float4(0.f, 0.f, 0.f, 0.f);
        if (d < 6) v = *(const float4*)&Zj[((size_t)(b * S_ + j0 + r)) * D_ + 4 * d];
        *(float4*)&sZj32[r * 32 + 4 * d] = v;
    }
    for (int t = tid; t < 512; t += 256) {   // zi32: 64 rows x 8 granules
        int r = t >> 3, d = t & 7;
        int gr = d ^ (r & 7);
        float4 v = make_float4(0.f, 0.f, 0.f, 0.f);
        if (d < 6) v = *(const float4*)&Zi[((size_t)(b * S_ + i0 + r)) * D_ + 4 * d];
        *(float4*)&sZi32[r * 32 + 4 * gr] = v;
    }
    {                                   // zi16: 64 rows x 4 granules (8 shorts)
        int r = tid >> 2, c = tid & 3;
        int gr = c ^ (r & 7);
        union { unsigned u[4]; bf16x8 v; } U;
        U.u[0] = U.u[1] = U.u[2] = U.u[3] = 0;
        if (c < 3) {
            const float* src = &Zi[((size_t)(b * S_ + i0 + r)) * D_ + 8 * c];
            U.u[0] = cvtpk(src[0], src[1]);
            U.u[1] = cvtpk(src[2], src[3]);
            U.u[2] = cvtpk(src[4], src[5]);
            U.u[3] = cvtpk(src[6], src[7]);
        }
        *(bf16x8*)&sZi16[r * 64 + 8 * gr] = U.v;
    }
    if (tid < 96) sW2[tid] = Ws2[tid];
    __syncthreads();

    // ---- Aterm[j][k] = bs1[k] + W1a[k,:] . zj[j,:]  (fp32, Ws1 from global) ----
    for (int o = tid; o < 16 * 96; o += 256) {
        int j = o / 96, k = o - j * 96;
        const float* wk = Ws1 + (size_t)k * 96;
        float acc = bs1[k];
        #pragma unroll
        for (int d = 0; d < 24; ++d) acc += wk[d] * sZj32[j * 32 + d];
        sAterm[o] = acc;
    }

    // ---- weight fragments (A-operand): wf[s][nt], lane holds
    // Ws1[nt*16+q][24*(s+1) + 8g .. +7], zeros for g==3 (K-padding) ----
    bf16x8 wf[3][6];
    #pragma unroll
    for (int s = 0; s < 3; ++s)
        #pragma unroll
        for (int nt = 0; nt < 6; ++nt) {
            union { unsigned u[4]; bf16x8 v; } U;
            U.u[0] = U.u[1] = U.u[2] = U.u[3] = 0;
            if (g < 3) {
                const float* wp = Ws1 + (size_t)(nt * 16 + q) * 96 + 24 * (s + 1) + 8 * g;
                U.u[0] = cvtpk(wp[0], wp[1]);
                U.u[1] = cvtpk(wp[2], wp[3]);
                U.u[2] = cvtpk(wp[4], wp[5]);
                U.u[3] = cvtpk(wp[6], wp[7]);
            }
            wf[s][nt] = U.v;
        }
    const float b2 = bs2[0];
    __syncthreads();

    // w2 in regs (broadcast reads, k = nt*16 + 4g + r)
    f32x4 w2r[6];
    #pragma unroll
    for (int nt = 0; nt < 6; ++nt)
        w2r[nt] = *(const f32x4*)&sW2[nt * 16 + 4 * g];

    // ---- main loop: wave wv owns jj = wv*4+jq; 4 i-subtiles of 16 ----
    for (int jq = 0; jq < 4; ++jq) {
        const int jj = wv * 4 + jq;
        const f32x4 zjA = *(const f32x4*)&sZj32[jj * 32 + 8 * g];
        const f32x4 zjB = *(const f32x4*)&sZj32[jj * 32 + 8 * g + 4];
        const f32x2 zA0 = __builtin_shufflevector(zjA, zjA, 0, 1);
        const f32x2 zA1 = __builtin_shufflevector(zjA, zjA, 2, 3);
        const f32x2 zB0 = __builtin_shufflevector(zjB, zjB, 0, 1);
        const f32x2 zB1 = __builtin_shufflevector(zjB, zjB, 2, 3);
        float* Prow = &P[((size_t)(b * S_ + j0 + jj)) * S_ + i0];

        #pragma unroll
        for (int ib = 0; ib < 4; ++ib) {
            const int ii = ib * 16 + q;
            const int sw = ii & 7;
            bf16x8 af1 = *(const bf16x8*)&sZi16[ii * 64 + 8 * (g ^ sw)];
            f32x4 zi0 = *(const f32x4*)&sZi32[ii * 32 + 4 * ((2 * g) ^ sw)];
            f32x4 zi1 = *(const f32x4*)&sZi32[ii * 32 + 4 * ((2 * g + 1) ^ sw)];
            const f32x2 i00 = __builtin_shufflevector(zi0, zi0, 0, 1);
            const f32x2 i01 = __builtin_shufflevector(zi0, zi0, 2, 3);
            const f32x2 i10 = __builtin_shufflevector(zi1, zi1, 0, 1);
            const f32x2 i11 = __builtin_shufflevector(zi1, zi1, 2, 3);

            // hadamard: pk_mul + cvt_pk; absdiff: pk_sub + cvt_pk(|.|)
            f32x2 p0 = zA0 * i00, p1 = zA1 * i01, p2 = zB0 * i10, p3 = zB1 * i11;
            f32x2 d0 = zA0 - i00, d1 = zA1 - i01, d2 = zB0 - i10, d3 = zB1 - i11;
            union { unsigned u[4]; bf16x8 v; } A2, A3;
            A2.u[0] = cvtpk(p0.x, p0.y); A2.u[1] = cvtpk(p1.x, p1.y);
            A2.u[2] = cvtpk(p2.x, p2.y); A2.u[3] = cvtpk(p3.x, p3.y);
            A3.u[0] = cvtpk_abs(d0.x, d0.y); A3.u[1] = cvtpk_abs(d1.x, d1.y);
            A3.u[2] = cvtpk_abs(d2.x, d2.y); A3.u[3] = cvtpk_abs(d3.x, d3.y);

            f32x4 acc[6];
            #pragma unroll
            for (int nt = 0; nt < 6; ++nt)
                acc[nt] = *(const f32x4*)&sAterm[jj * 96 + nt * 16 + 4 * g];
            #pragma unroll
            for (int nt = 0; nt < 6; ++nt) {
                acc[nt] = __builtin_amdgcn_mfma_f32_16x16x32_bf16(wf[0][nt], af1,  acc[nt], 0, 0, 0);
                acc[nt] = __builtin_amdgcn_mfma_f32_16x16x32_bf16(wf[1][nt], A2.v, acc[nt], 0, 0, 0);
                acc[nt] = __builtin_amdgcn_mfma_f32_16x16x32_bf16(wf[2][nt], A3.v, acc[nt], 0, 0, 0);
            }

            // packed epilogue: lg2 += w2 * max(acc, 0)
            f32x2 lg2 = {0.f, 0.f};
            const f32x2 z2 = {0.f, 0.f};
            #pragma unroll
            for (int nt = 0; nt < 6; ++nt) {
                f32x2 alo = __builtin_shufflevector(acc[nt], acc[nt], 0, 1);
                f32x2 ahi = __builtin_shufflevector(acc[nt], acc[nt], 2, 3);
                f32x2 wlo = __builtin_shufflevector(w2r[nt], w2r[nt], 0, 1);
                f32x2 whi = __builtin_shufflevector(w2r[nt], w2r[nt], 2, 3);
                lg2 += wlo * __builtin_elementwise_max(alo, z2);
                lg2 += whi * __builtin_elementwise_max(ahi, z2);
            }
            float lg = lg2.x + lg2.y;
            lg += __shfl_xor(lg, 16);
            lg += __shfl_xor(lg, 32);
            if (lane < 16) Prow[ib * 16 + lane] = lg + b2;
        }
    }
}

// ---------------------------------------------------------------------------
// K3: row softmax over i (additive key mask); reads fp32 logits, writes bf16
// ---------------------------------------------------------------------------
__global__ __launch_bounds__(256) void softmax_kernel(
    const float* __restrict__ mask, const float* __restrict__ P,
    u16* __restrict__ Pb)
{
    const int r = blockIdx.x;           // b*S + j
    const int b = r / S_;
    const int tid = threadIdx.x;
    const float* row = P + (size_t)r * S_;
    __shared__ float red[4];

    float v[4];
    float mx = -INFINITY;
    #pragma unroll
    for (int c = 0; c < 4; ++c) {
        int i = tid + 256 * c;
        float m = mask[b * S_ + i];
        v[c] = row[i] + (1.0f - m) * NEGF;
        mx = fmaxf(mx, v[c]);
    }
    for (int off = 32; off > 0; off >>= 1) mx = fmaxf(mx, __shfl_xor(mx, off));
    if ((tid & 63) == 0) red[tid >> 6] = mx;
    __syncthreads();
    mx = fmaxf(fmaxf(red[0], red[1]), fmaxf(red[2], red[3]));

    float s = 0.f;
    #pragma unroll
    for (int c = 0; c < 4; ++c) { v[c] = __expf(v[c] - mx); s += v[c]; }
    for (int off = 32; off > 0; off >>= 1) s += __shfl_xor(s, off);
    __syncthreads();
    if ((tid & 63) == 0) red[tid >> 6] = s;
    __syncthreads();
    s = red[0] + red[1] + red[2] + red[3];
    const float inv = 1.0f / s;
    #pragma unroll
    for (int c = 0; c < 4; ++c)
        Pb[(size_t)r * S_ + tid + 256 * c] = (u16)f2bf(v[c] * inv);
}

// ---------------------------------------------------------------------------
// Prep kernels: fp32->bf16 convert, Hi transpose, msg_in build
// ---------------------------------------------------------------------------
__global__ __launch_bounds__(256) void cvt_kernel(
    const float* __restrict__ src, u16* __restrict__ dst, int n4)
{
    int i = blockIdx.x * 256 + threadIdx.x;
    if (i >= n4) return;
    float4 v = ((const float4*)src)[i];
    unsigned lo = cvtpk(v.x, v.y), hi = cvtpk(v.z, v.w);
    ((uint2*)dst)[i] = make_uint2(lo, hi);
}

__global__ __launch_bounds__(256) void transpose_hi_kernel(
    const float* __restrict__ Hi, u16* __restrict__ HiT)
{
    __shared__ u16 t[32][33];
    const int i0 = blockIdx.x * 32, h0 = blockIdx.y * 32, b = blockIdx.z;
    const int c = threadIdx.x & 31, r = threadIdx.x >> 5;   // r: 0..7
    #pragma unroll
    for (int rr = r; rr < 32; rr += 8)
        t[rr][c] = (u16)f2bf(Hi[((size_t)(b * S_ + i0 + rr)) * H_ + h0 + c]);
    __syncthreads();
    #pragma unroll
    for (int rr = r; rr < 32; rr += 8)
        HiT[((size_t)(b * H_ + h0 + rr)) * S_ + i0 + c] = t[c][rr];
}

__global__ __launch_bounds__(256) void msgin_kernel(
    const u16* __restrict__ ctx, const float* __restrict__ Hj,
    u16* __restrict__ MSG)
{
    const int idx = blockIdx.x * 256 + threadIdx.x;   // < 2048*96
    const int m = idx / 96, c8 = (idx % 96) * 8;
    bf16x8 c = *(const bf16x8*)&ctx[(size_t)m * H_ + c8];
    float4 h0 = *(const float4*)&Hj[(size_t)m * H_ + c8];
    float4 h1 = *(const float4*)&Hj[(size_t)m * H_ + c8 + 4];
    float hf[8] = {h0.x, h0.y, h0.z, h0.w, h1.x, h1.y, h1.z, h1.w};
    union { unsigned u[4]; bf16x8 v; } HB, PB;
    HB.u[0] = cvtpk(hf[0], hf[1]); HB.u[1] = cvtpk(hf[2], hf[3]);
    HB.u[2] = cvtpk(hf[4], hf[5]); HB.u[3] = cvtpk(hf[6], hf[7]);
    float pf[8];
    #pragma unroll
    for (int e = 0; e < 8; ++e) pf[e] = bf2f(c[e]) * hf[e];
    PB.u[0] = cvtpk(pf[0], pf[1]); PB.u[1] = cvtpk(pf[2], pf[3]);
    PB.u[2] = cvtpk(pf[4], pf[5]); PB.u[3] = cvtpk(pf[6], pf[7]);
    u16* row = MSG + (size_t)m * VI_;
    *(bf16x8*)&row[c8]        = c;
    *(bf16x8*)&row[768 + c8]  = HB.v;
    *(bf16x8*)&row[1536 + c8] = PB.v;
}

// ---------------------------------------------------------------------------
// bf16 MFMA GEMM: C[2048,768] = A[2048,K] x B[768,K]^T
// 64x64 tile, BK=64, 4 waves (2x2, 32x32 each), dbuf LDS, global_load_lds(16),
// chunk-XOR swizzle (c ^= row&7) pre-applied on global source, applied on read.
// ---------------------------------------------------------------------------
template<int MODE, int K>
__global__ __launch_bounds__(256) void mfma_gemm_kernel(
    const u16* __restrict__ Ag, const u16* __restrict__ Bg,
    const float* __restrict__ bias, const float* __restrict__ alphaPtr,
    void* __restrict__ Outv)
{
    __shared__ u16 As[2][64 * 64];
    __shared__ u16 Bs[2][64 * 64];
    const int tid = threadIdx.x;
    const int lane = tid & 63, wv = tid >> 6;
    const int q = lane & 15, g = lane >> 4;
    const int wr = wv >> 1, wc = wv & 1;
    const int m0 = blockIdx.x * 64, n0 = blockIdx.y * 64;

    const u16* Ab = Ag + (size_t)m0 * K;
    const u16* Bb = (MODE == 0)
        ? Bg + (size_t)(m0 >> 10) * H_ * S_ + (size_t)n0 * K
        : Bg + (size_t)n0 * K;

    int st_r[2], st_gc[2], st_dst[2];
    #pragma unroll
    for (int it = 0; it < 2; ++it) {
        int cidx = (it * 4 + wv) * 64 + lane;
        st_r[it] = cidx >> 3;
        st_gc[it] = (cidx & 7) ^ (st_r[it] & 7);
        st_dst[it] = cidx * 8;
    }

    f32x4 acc[2][2] = {};

    auto stage = [&](int buf, int k0) {
        #pragma unroll
        for (int it = 0; it < 2; ++it) {
            gl_lds16(Ab + (size_t)st_r[it] * K + k0 + st_gc[it] * 8,
                     &As[buf][st_dst[it]]);
            gl_lds16(Bb + (size_t)st_r[it] * K + k0 + st_gc[it] * 8,
                     &Bs[buf][st_dst[it]]);
        }
    };
    auto comp = [&](int buf) {
        #pragma unroll
        for (int ks = 0; ks < 2; ++ks) {
            bf16x8 af[2], bfr[2];
            #pragma unroll
            for (int m = 0; m < 2; ++m) {
                int r = wr * 32 + m * 16 + q;
                int cl = (g + ks * 4) ^ (r & 7);
                af[m] = *(const bf16x8*)&As[buf][r * 64 + cl * 8];
            }
            #pragma unroll
            for (int n = 0; n < 2; ++n) {
                int r = wc * 32 + n * 16 + q;
                int cl = (g + ks * 4) ^ (r & 7);
                bfr[n] = *(const bf16x8*)&Bs[buf][r * 64 + cl * 8];
            }
            #pragma unroll
            for (int m = 0; m < 2; ++m)
                #pragma unroll
                for (int n = 0; n < 2; ++n)
                    acc[m][n] = __builtin_amdgcn_mfma_f32_16x16x32_bf16(
                        af[m], bfr[n], acc[m][n], 0, 0, 0);
        }
    };

    constexpr int NT = K / 64;
    stage(0, 0);
    __syncthreads();
    int cur = 0;
    for (int kt = 0; kt < NT - 1; ++kt) {
        stage(cur ^ 1, (kt + 1) * 64);
        comp(cur);
        __syncthreads();
        cur ^= 1;
    }
    comp(cur);

    const float alpha = (MODE == 2) ? alphaPtr[0] : 0.f;
    u16* O16 = (u16*)Outv;
    float* Of = (float*)Outv;
    #pragma unroll
    for (int m = 0; m < 2; ++m) {
        #pragma unroll
        for (int n = 0; n < 2; ++n) {
            const int col = n0 + wc * 32 + n * 16 + q;
            const float bn = (MODE == 0) ? 0.f : bias[col];
            #pragma unroll
            for (int rg = 0; rg < 4; ++rg) {
                const int row = m0 + wr * 32 + m * 16 + g * 4 + rg;
                float v = acc[m][n][rg];
                if (MODE == 0)      O16[(size_t)row * H_ + col] = (u16)f2bf(v);
                else if (MODE == 1) O16[(size_t)row * H_ + col] = (u16)f2bf(relu_(v + bn));
                else                Of[(size_t)row * H_ + col] = alpha * (v + bn);
            }
        }
    }
}

// ---------------------------------------------------------------------------
extern "C" void kernel_launch(void* const* d_in, const int* in_sizes, int n_in,
                              void* d_out, int out_size, void* d_ws, size_t ws_size,
                              hipStream_t stream)
{
    (void)in_sizes; (void)n_in; (void)out_size; (void)ws_size;
    const float* Hj   = (const float*)d_in[0];
    const float* Hi   = (const float*)d_in[1];
    const float* mask = (const float*)d_in[2];
    const float* Wpj  = (const float*)d_in[3];
    const float* Wpi  = (const float*)d_in[4];
    const float* Ws1  = (const float*)d_in[5];
    const float* bs1  = (const float*)d_in[6];
    const float* Ws2  = (const float*)d_in[7];
    const float* bs2  = (const float*)d_in[8];
    const float* Wv1  = (const float*)d_in[9];
    const float* bv1  = (const float*)d_in[10];
    const float* Wv2  = (const float*)d_in[11];
    const float* bv2  = (const float*)d_in[12];
    const float* alphaPtr = (const float*)d_in[13];
    float* out = (float*)d_out;

    char* w = (char*)d_ws;
    float* Zj   = (float*)(w);                       // 196608 B
    float* Zi   = (float*)(w + 196608);              // 196608 B
    size_t oPlog = 393216;
    size_t oPb   = oPlog + 8388608;    // 8781824
    size_t oHiT  = oPb + 4194304;      // 12976128
    size_t oWv1b = oHiT + 3145728;     // 16121856
    size_t oWv2b = oWv1b + 3538944;    // 19660800
    size_t oCTX  = oWv2b + 1179648;    // 20840448; end ~24 MB
    float* Plog = (float*)(w + oPlog);
    u16* Pb   = (u16*)(w + oPb);
    u16* HiT  = (u16*)(w + oHiT);
    u16* Wv1b = (u16*)(w + oWv1b);
    u16* Wv2b = (u16*)(w + oWv2b);
    u16* CTX  = (u16*)(w + oCTX);
    u16* MSG  = (u16*)(w + oPlog);     // overlay Plog+Pb (dead by then)
    u16* X1   = (u16*)(w + oHiT);      // overlay HiT (dead after gemm0)

    cvt_kernel<<<(H_ * VI_ / 4 + 255) / 256, 256, 0, stream>>>(Wv1, Wv1b, H_ * VI_ / 4);
    cvt_kernel<<<(H_ * OH_ / 4 + 255) / 256, 256, 0, stream>>>(Wv2, Wv2b, H_ * OH_ / 4);
    transpose_hi_kernel<<<dim3(S_ / 32, H_ / 32, B_), 256, 0, stream>>>(Hi, HiT);

    proj_kernel<<<B_ * S_, 256, 0, stream>>>(Hj, Hi, Wpj, Wpi, Zj, Zi);
    pair_mfma_kernel<<<dim3(S_ / 16, S_ / 64, B_), 256, 0, stream>>>(
        Zj, Zi, Ws1, Ws2, bs1, bs2, Plog);
    softmax_kernel<<<B_ * S_, 256, 0, stream>>>(mask, Plog, Pb);

    mfma_gemm_kernel<0, S_><<<dim3(2048 / 64, H_ / 64), 256, 0, stream>>>(
        Pb, HiT, nullptr, nullptr, CTX);
    msgin_kernel<<<(2048 * 96) / 256, 256, 0, stream>>>(CTX, Hj, MSG);
    mfma_gemm_kernel<1, VI_><<<dim3(2048 / 64, OH_ / 64), 256, 0, stream>>>(
        MSG, Wv1b, bv1, nullptr, X1);
    mfma_gemm_kernel<2, OH_><<<dim3(2048 / 64, H_ / 64), 256, 0, stream>>>(
        X1, Wv2b, bv2, alphaPtr, out);
}

// Round 6
// 246.082 us; speedup vs baseline: 1.1352x; 1.1352x over previous
//
#include <hip/hip_runtime.h>
#include <hip/hip_bf16.h>
#include <math.h>

#define B_ 2
#define S_ 1024
#define H_ 768
#define D_ 24
#define HID_ 96
#define OH_ 768
#define VI_ 2304

typedef short bf16x8 __attribute__((ext_vector_type(8)));
typedef _Float16 f16x8 __attribute__((ext_vector_type(8)));
typedef float f32x4 __attribute__((ext_vector_type(4)));
typedef unsigned short u16;

static __device__ __forceinline__ float relu_(float x) { return x > 0.f ? x : 0.f; }

static __device__ __forceinline__ short f2bf(float f) {
    __hip_bfloat16 h = __float2bfloat16(f);
    return *reinterpret_cast<short*>(&h);
}
static __device__ __forceinline__ float bf2f(short s) {
    unsigned u = ((unsigned)(u16)s) << 16;
    return __uint_as_float(u);
}

static __device__ __forceinline__ void gl_lds16(const void* g, void* l) {
    __builtin_amdgcn_global_load_lds(
        (const __attribute__((address_space(1))) unsigned int*)g,
        (__attribute__((address_space(3))) unsigned int*)l, 16, 0, 0);
}

#define NEGF (-3.402823466e38f)

// ---------------------------------------------------------------------------
// K1: per-token projections Zj, Zi  [B,S,D]
// ---------------------------------------------------------------------------
__global__ __launch_bounds__(256) void proj_kernel(
    const float* __restrict__ Hj, const float* __restrict__ Hi,
    const float* __restrict__ Wpj, const float* __restrict__ Wpi,
    float* __restrict__ Zj, float* __restrict__ Zi)
{
    __shared__ float rowj[H_], rowi[H_];
    const int t = blockIdx.x;           // 0..B*S-1
    const int tid = threadIdx.x;
    const float* hj = Hj + (size_t)t * H_;
    const float* hi = Hi + (size_t)t * H_;
    for (int x = tid; x < H_; x += 256) { rowj[x] = hj[x]; rowi[x] = hi[x]; }
    __syncthreads();

    const int g = tid & 7;              // 8 threads per output
    for (int o = tid >> 3; o < 2 * D_; o += 32) {
        const float* row;
        const float* w;
        if (o < D_) { row = rowj; w = Wpj + o * H_; }
        else        { row = rowi; w = Wpi + (o - D_) * H_; }
        float s = 0.f;
        #pragma unroll 8
        for (int c = 0; c < H_ / 8; ++c) s += row[g + 8 * c] * w[g + 8 * c];
        s += __shfl_down(s, 4, 8);
        s += __shfl_down(s, 2, 8);
        s += __shfl_down(s, 1, 8);
        if (g == 0) {
            if (o < D_) Zj[(size_t)t * D_ + o] = s;
            else        Zi[(size_t)t * D_ + (o - D_)] = s;
        }
    }
}

// ---------------------------------------------------------------------------
// K2: pair logits via f16 MFMA, divergence-free, zero conversions in hot loop.
// Feature K-steps: s0=[Zi|0*8], s1=[Zj*Zi|0*8], s2=[|Zj-Zi||0*8] built with
// packed f16 ALU directly from the MFMA fragment registers. Zj-linear + bias
// folded into Aterm (fp32 C-in). mfma(W, F, acc): D row=k, col=pair.
// ---------------------------------------------------------------------------
__global__ __launch_bounds__(256) void pair_mfma_kernel(
    const float* __restrict__ Zj, const float* __restrict__ Zi,
    const float* __restrict__ Ws1, const float* __restrict__ Ws2,
    const float* __restrict__ bs1, const float* __restrict__ bs2,
    float* __restrict__ P)
{
    __shared__ float    sZj32[16 * 32];   // f32, cols 24..31 = 0 (for Aterm)
    __shared__ _Float16 sZj16[16 * 32];   // f16, cols 24..31 = 0
    __shared__ _Float16 sZi16[64 * 64];   // 8 granule slots/row; chunk c at c^(r&7), c<4
    __shared__ float    sAterm[16 * 96];  // [j][k]
    __shared__ float    sW1a[96 * 25];
    __shared__ float    sW2[96];

    const int j0 = blockIdx.x * 16, i0 = blockIdx.y * 64, b = blockIdx.z;
    const int tid = threadIdx.x;
    const int lane = tid & 63;
    const int wv = tid >> 6;
    const int q = lane & 15, g = lane >> 4;

    // ---- stage tiles ----
    if (tid < 128) {                    // zj: 16 rows x 8 granules of 4
        int r = tid >> 3, d = tid & 7;
        float4 v = make_float4(0.f, 0.f, 0.f, 0.f);
        if (d < 6) v = *(const float4*)&Zj[((size_t)(b * S_ + j0 + r)) * D_ + 4 * d];
        *(float4*)&sZj32[r * 32 + 4 * d] = v;
        _Float16 h4[4] = {(_Float16)v.x, (_Float16)v.y, (_Float16)v.z, (_Float16)v.w};
        *(ushort4*)&sZj16[r * 32 + 4 * d] = *(const ushort4*)h4;
    }
    {                                   // zi16: 64 rows x 4 data chunks of 8
        int r = tid >> 2, c = tid & 3;
        int gr = c ^ (r & 7);
        f16x8 o = {0, 0, 0, 0, 0, 0, 0, 0};
        if (c < 3) {
            const float* src = &Zi[((size_t)(b * S_ + i0 + r)) * D_ + 8 * c];
            #pragma unroll
            for (int e = 0; e < 8; ++e) o[e] = (_Float16)src[e];
        }
        *(f16x8*)&sZi16[r * 64 + 8 * gr] = o;
    }
    for (int t = tid; t < 96 * 24; t += 256) {
        int k = t / 24, d = t - k * 24;
        sW1a[k * 25 + d] = Ws1[(size_t)k * 96 + d];
    }
    if (tid < 96) sW2[tid] = Ws2[tid];
    __syncthreads();

    // ---- Aterm[j][k] = bs1[k] + W1a[k,:] . zj[j,:]  (fp32) ----
    for (int o = tid; o < 16 * 96; o += 256) {
        int j = o / 96, k = o - j * 96;
        float acc = bs1[k];
        #pragma unroll
        for (int d = 0; d < 24; ++d) acc += sW1a[k * 25 + d] * sZj32[j * 32 + d];
        sAterm[o] = acc;
    }

    // ---- weight fragments (A-operand, f16): wf[s][nt], lane holds
    // Ws1[nt*16+q][24*(s+1) + 8g .. +7], zeros for g==3 (K-padding) ----
    f16x8 wf[3][6];
    #pragma unroll
    for (int s = 0; s < 3; ++s)
        #pragma unroll
        for (int nt = 0; nt < 6; ++nt) {
            f16x8 t8 = {0, 0, 0, 0, 0, 0, 0, 0};
            if (g < 3) {
                const float* wp = Ws1 + (size_t)(nt * 16 + q) * 96 + 24 * (s + 1) + 8 * g;
                #pragma unroll
                for (int e = 0; e < 8; ++e) t8[e] = (_Float16)wp[e];
            }
            wf[s][nt] = t8;
        }
    const float b2 = bs2[0];
    __syncthreads();

    // w2 in regs (broadcast reads, k = nt*16 + 4g + r)
    f32x4 w2r[6];
    #pragma unroll
    for (int nt = 0; nt < 6; ++nt)
        w2r[nt] = *(const f32x4*)&sW2[nt * 16 + 4 * g];
    const f32x4 zero4 = {0.f, 0.f, 0.f, 0.f};

    // ---- main loop: wave wv owns jj = wv*4+jq; 4 i-subtiles of 16 ----
    for (int jq = 0; jq < 4; ++jq) {
        const int jj = wv * 4 + jq;
        const f16x8 zjh = *(const f16x8*)&sZj16[jj * 32 + 8 * g];  // broadcast
        f32x4 At[6];
        #pragma unroll
        for (int nt = 0; nt < 6; ++nt)
            At[nt] = *(const f32x4*)&sAterm[jj * 96 + nt * 16 + 4 * g];
        float* Prow = &P[((size_t)(b * S_ + j0 + jj)) * S_ + i0];

        #pragma unroll
        for (int ib = 0; ib < 4; ++ib) {
            const int ii = ib * 16 + q;
            const int sw = ii & 7;
            const f16x8 af1 = *(const f16x8*)&sZi16[ii * 64 + 8 * (g ^ sw)];
            const f16x8 a2 = zjh * af1;            // v_pk_mul_f16 x4
            const f16x8 dd = zjh - af1;            // v_pk_add_f16 x4
            const f16x8 a3 = __builtin_elementwise_max(dd, -dd);  // v_pk_max_f16 x4

            f32x4 acc[6];
            #pragma unroll
            for (int nt = 0; nt < 6; ++nt) acc[nt] = At[nt];
            #pragma unroll
            for (int nt = 0; nt < 6; ++nt) {
                acc[nt] = __builtin_amdgcn_mfma_f32_16x16x32_f16(wf[0][nt], af1, acc[nt], 0, 0, 0);
                acc[nt] = __builtin_amdgcn_mfma_f32_16x16x32_f16(wf[1][nt], a2,  acc[nt], 0, 0, 0);
                acc[nt] = __builtin_amdgcn_mfma_f32_16x16x32_f16(wf[2][nt], a3,  acc[nt], 0, 0, 0);
            }

            // packed epilogue: lgv += w2 * max(acc, 0)
            f32x4 lgv = zero4;
            #pragma unroll
            for (int nt = 0; nt < 6; ++nt)
                lgv += w2r[nt] * __builtin_elementwise_max(acc[nt], zero4);
            float lg = (lgv[0] + lgv[1]) + (lgv[2] + lgv[3]);
            lg += __shfl_xor(lg, 16);
            lg += __shfl_xor(lg, 32);
            if (lane < 16) Prow[ib * 16 + lane] = lg + b2;
        }
    }
}

// ---------------------------------------------------------------------------
// K3: row softmax over i (additive key mask); reads fp32 logits, writes bf16
// ---------------------------------------------------------------------------
__global__ __launch_bounds__(256) void softmax_kernel(
    const float* __restrict__ mask, const float* __restrict__ P,
    u16* __restrict__ Pb)
{
    const int r = blockIdx.x;           // b*S + j
    const int b = r / S_;
    const int tid = threadIdx.x;
    const float* row = P + (size_t)r * S_;
    __shared__ float red[4];

    float v[4];
    float mx = -INFINITY;
    #pragma unroll
    for (int c = 0; c < 4; ++c) {
        int i = tid + 256 * c;
        float m = mask[b * S_ + i];
        v[c] = row[i] + (1.0f - m) * NEGF;
        mx = fmaxf(mx, v[c]);
    }
    for (int off = 32; off > 0; off >>= 1) mx = fmaxf(mx, __shfl_xor(mx, off));
    if ((tid & 63) == 0) red[tid >> 6] = mx;
    __syncthreads();
    mx = fmaxf(fmaxf(red[0], red[1]), fmaxf(red[2], red[3]));

    float s = 0.f;
    #pragma unroll
    for (int c = 0; c < 4; ++c) { v[c] = __expf(v[c] - mx); s += v[c]; }
    for (int off = 32; off > 0; off >>= 1) s += __shfl_xor(s, off);
    __syncthreads();
    if ((tid & 63) == 0) red[tid >> 6] = s;
    __syncthreads();
    s = red[0] + red[1] + red[2] + red[3];
    const float inv = 1.0f / s;
    #pragma unroll
    for (int c = 0; c < 4; ++c)
        Pb[(size_t)r * S_ + tid + 256 * c] = (u16)f2bf(v[c] * inv);
}

// ---------------------------------------------------------------------------
// Prep kernels: fp32->bf16 convert, Hi transpose, msg_in build
// ---------------------------------------------------------------------------
__global__ __launch_bounds__(256) void cvt_kernel(
    const float* __restrict__ src, u16* __restrict__ dst, int n4)
{
    int i = blockIdx.x * 256 + threadIdx.x;
    if (i >= n4) return;
    float4 v = ((const float4*)src)[i];
    ushort4 o;
    o.x = (u16)f2bf(v.x); o.y = (u16)f2bf(v.y);
    o.z = (u16)f2bf(v.z); o.w = (u16)f2bf(v.w);
    ((ushort4*)dst)[i] = o;
}

__global__ __launch_bounds__(256) void transpose_hi_kernel(
    const float* __restrict__ Hi, u16* __restrict__ HiT)
{
    __shared__ u16 t[32][33];
    const int i0 = blockIdx.x * 32, h0 = blockIdx.y * 32, b = blockIdx.z;
    const int c = threadIdx.x & 31, r = threadIdx.x >> 5;   // r: 0..7
    #pragma unroll
    for (int rr = r; rr < 32; rr += 8)
        t[rr][c] = (u16)f2bf(Hi[((size_t)(b * S_ + i0 + rr)) * H_ + h0 + c]);
    __syncthreads();
    #pragma unroll
    for (int rr = r; rr < 32; rr += 8)
        HiT[((size_t)(b * H_ + h0 + rr)) * S_ + i0 + c] = t[c][rr];
}

__global__ __launch_bounds__(256) void msgin_kernel(
    const u16* __restrict__ ctx, const float* __restrict__ Hj,
    u16* __restrict__ MSG)
{
    const int idx = blockIdx.x * 256 + threadIdx.x;   // < 2048*96
    const int m = idx / 96, c8 = (idx % 96) * 8;
    bf16x8 c = *(const bf16x8*)&ctx[(size_t)m * H_ + c8];
    float4 h0 = *(const float4*)&Hj[(size_t)m * H_ + c8];
    float4 h1 = *(const float4*)&Hj[(size_t)m * H_ + c8 + 4];
    float hf[8] = {h0.x, h0.y, h0.z, h0.w, h1.x, h1.y, h1.z, h1.w};
    bf16x8 hb, pb;
    #pragma unroll
    for (int e = 0; e < 8; ++e) {
        hb[e] = f2bf(hf[e]);
        pb[e] = f2bf(bf2f(c[e]) * hf[e]);
    }
    u16* row = MSG + (size_t)m * VI_;
    *(bf16x8*)&row[c8]        = c;
    *(bf16x8*)&row[768 + c8]  = hb;
    *(bf16x8*)&row[1536 + c8] = pb;
}

// ---------------------------------------------------------------------------
// bf16 MFMA GEMM: C[2048,768] = A[2048,K] x B[768,K]^T
// 64x64 tile, BK=64, 4 waves (2x2, 32x32 each), dbuf LDS, global_load_lds(16),
// chunk-XOR swizzle (c ^= row&7) pre-applied on global source, applied on read.
// ---------------------------------------------------------------------------
template<int MODE, int K>
__global__ __launch_bounds__(256) void mfma_gemm_kernel(
    const u16* __restrict__ Ag, const u16* __restrict__ Bg,
    const float* __restrict__ bias, const float* __restrict__ alphaPtr,
    void* __restrict__ Outv)
{
    __shared__ u16 As[2][64 * 64];
    __shared__ u16 Bs[2][64 * 64];
    const int tid = threadIdx.x;
    const int lane = tid & 63, wv = tid >> 6;
    const int q = lane & 15, g = lane >> 4;
    const int wr = wv >> 1, wc = wv & 1;
    const int m0 = blockIdx.x * 64, n0 = blockIdx.y * 64;

    const u16* Ab = Ag + (size_t)m0 * K;
    const u16* Bb = (MODE == 0)
        ? Bg + (size_t)(m0 >> 10) * H_ * S_ + (size_t)n0 * K
        : Bg + (size_t)n0 * K;

    int st_r[2], st_gc[2], st_dst[2];
    #pragma unroll
    for (int it = 0; it < 2; ++it) {
        int cidx = (it * 4 + wv) * 64 + lane;
        st_r[it] = cidx >> 3;
        st_gc[it] = (cidx & 7) ^ (st_r[it] & 7);
        st_dst[it] = cidx * 8;
    }

    f32x4 acc[2][2] = {};

    auto stage = [&](int buf, int k0) {
        #pragma unroll
        for (int it = 0; it < 2; ++it) {
            gl_lds16(Ab + (size_t)st_r[it] * K + k0 + st_gc[it] * 8,
                     &As[buf][st_dst[it]]);
            gl_lds16(Bb + (size_t)st_r[it] * K + k0 + st_gc[it] * 8,
                     &Bs[buf][st_dst[it]]);
        }
    };
    auto comp = [&](int buf) {
        #pragma unroll
        for (int ks = 0; ks < 2; ++ks) {
            bf16x8 af[2], bfr[2];
            #pragma unroll
            for (int m = 0; m < 2; ++m) {
                int r = wr * 32 + m * 16 + q;
                int cl = (g + ks * 4) ^ (r & 7);
                af[m] = *(const bf16x8*)&As[buf][r * 64 + cl * 8];
            }
            #pragma unroll
            for (int n = 0; n < 2; ++n) {
                int r = wc * 32 + n * 16 + q;
                int cl = (g + ks * 4) ^ (r & 7);
                bfr[n] = *(const bf16x8*)&Bs[buf][r * 64 + cl * 8];
            }
            #pragma unroll
            for (int m = 0; m < 2; ++m)
                #pragma unroll
                for (int n = 0; n < 2; ++n)
                    acc[m][n] = __builtin_amdgcn_mfma_f32_16x16x32_bf16(
                        af[m], bfr[n], acc[m][n], 0, 0, 0);
        }
    };

    constexpr int NT = K / 64;
    stage(0, 0);
    __syncthreads();
    int cur = 0;
    for (int kt = 0; kt < NT - 1; ++kt) {
        stage(cur ^ 1, (kt + 1) * 64);
        comp(cur);
        __syncthreads();
        cur ^= 1;
    }
    comp(cur);

    const float alpha = (MODE == 2) ? alphaPtr[0] : 0.f;
    u16* O16 = (u16*)Outv;
    float* Of = (float*)Outv;
    #pragma unroll
    for (int m = 0; m < 2; ++m) {
        #pragma unroll
        for (int n = 0; n < 2; ++n) {
            const int col = n0 + wc * 32 + n * 16 + q;
            const float bn = (MODE == 0) ? 0.f : bias[col];
            #pragma unroll
            for (int rg = 0; rg < 4; ++rg) {
                const int row = m0 + wr * 32 + m * 16 + g * 4 + rg;
                float v = acc[m][n][rg];
                if (MODE == 0)      O16[(size_t)row * H_ + col] = (u16)f2bf(v);
                else if (MODE == 1) O16[(size_t)row * H_ + col] = (u16)f2bf(relu_(v + bn));
                else                Of[(size_t)row * H_ + col] = alpha * (v + bn);
            }
        }
    }
}

// ---------------------------------------------------------------------------
extern "C" void kernel_launch(void* const* d_in, const int* in_sizes, int n_in,
                              void* d_out, int out_size, void* d_ws, size_t ws_size,
                              hipStream_t stream)
{
    (void)in_sizes; (void)n_in; (void)out_size; (void)ws_size;
    const float* Hj   = (const float*)d_in[0];
    const float* Hi   = (const float*)d_in[1];
    const float* mask = (const float*)d_in[2];
    const float* Wpj  = (const float*)d_in[3];
    const float* Wpi  = (const float*)d_in[4];
    const float* Ws1  = (const float*)d_in[5];
    const float* bs1  = (const float*)d_in[6];
    const float* Ws2  = (const float*)d_in[7];
    const float* bs2  = (const float*)d_in[8];
    const float* Wv1  = (const float*)d_in[9];
    const float* bv1  = (const float*)d_in[10];
    const float* Wv2  = (const float*)d_in[11];
    const float* bv2  = (const float*)d_in[12];
    const float* alphaPtr = (const float*)d_in[13];
    float* out = (float*)d_out;

    char* w = (char*)d_ws;
    float* Zj   = (float*)(w);                       // 196608 B
    float* Zi   = (float*)(w + 196608);              // 196608 B
    size_t oPlog = 393216;
    size_t oPb   = oPlog + 8388608;    // 8781824
    size_t oHiT  = oPb + 4194304;      // 12976128
    size_t oWv1b = oHiT + 3145728;     // 16121856
    size_t oWv2b = oWv1b + 3538944;    // 19660800
    size_t oCTX  = oWv2b + 1179648;    // 20840448; end ~24 MB
    float* Plog = (float*)(w + oPlog);
    u16* Pb   = (u16*)(w + oPb);
    u16* HiT  = (u16*)(w + oHiT);
    u16* Wv1b = (u16*)(w + oWv1b);
    u16* Wv2b = (u16*)(w + oWv2b);
    u16* CTX  = (u16*)(w + oCTX);
    u16* MSG  = (u16*)(w + oPlog);     // overlay Plog+Pb (dead by then)
    u16* X1   = (u16*)(w + oHiT);      // overlay HiT (dead after gemm0)

    cvt_kernel<<<(H_ * VI_ / 4 + 255) / 256, 256, 0, stream>>>(Wv1, Wv1b, H_ * VI_ / 4);
    cvt_kernel<<<(H_ * OH_ / 4 + 255) / 256, 256, 0, stream>>>(Wv2, Wv2b, H_ * OH_ / 4);
    transpose_hi_kernel<<<dim3(S_ / 32, H_ / 32, B_), 256, 0, stream>>>(Hi, HiT);

    proj_kernel<<<B_ * S_, 256, 0, stream>>>(Hj, Hi, Wpj, Wpi, Zj, Zi);
    pair_mfma_kernel<<<dim3(S_ / 16, S_ / 64, B_), 256, 0, stream>>>(
        Zj, Zi, Ws1, Ws2, bs1, bs2, Plog);
    softmax_kernel<<<B_ * S_, 256, 0, stream>>>(mask, Plog, Pb);

    mfma_gemm_kernel<0, S_><<<dim3(2048 / 64, H_ / 64), 256, 0, stream>>>(
        Pb, HiT, nullptr, nullptr, CTX);
    msgin_kernel<<<(2048 * 96) / 256, 256, 0, stream>>>(CTX, Hj, MSG);
    mfma_gemm_kernel<1, VI_><<<dim3(2048 / 64, OH_ / 64), 256, 0, stream>>>(
        MSG, Wv1b, bv1, nullptr, X1);
    mfma_gemm_kernel<2, OH_><<<dim3(2048 / 64, H_ / 64), 256, 0, stream>>>(
        X1, Wv2b, bv2, alphaPtr, out);
}

// Round 8
// 232.150 us; speedup vs baseline: 1.2033x; 1.0600x over previous
//
#include <hip/hip_runtime.h>
#include <hip/hip_bf16.h>
#include <math.h>

#define B_ 2
#define S_ 1024
#define H_ 768
#define D_ 24
#define HID_ 96
#define OH_ 768
#define VI_ 2304

typedef short bf16x8 __attribute__((ext_vector_type(8)));
typedef _Float16 f16x8 __attribute__((ext_vector_type(8)));
typedef float f32x4 __attribute__((ext_vector_type(4)));
typedef unsigned short u16;

static __device__ __forceinline__ float relu_(float x) { return x > 0.f ? x : 0.f; }

static __device__ __forceinline__ short f2bf(float f) {
    __hip_bfloat16 h = __float2bfloat16(f);
    return *reinterpret_cast<short*>(&h);
}
static __device__ __forceinline__ float bf2f(short s) {
    unsigned u = ((unsigned)(u16)s) << 16;
    return __uint_as_float(u);
}

static __device__ __forceinline__ void gl_lds16(const void* g, void* l) {
    __builtin_amdgcn_global_load_lds(
        (const __attribute__((address_space(1))) unsigned int*)g,
        (__attribute__((address_space(3))) unsigned int*)l, 16, 0, 0);
}

#define NEGF (-3.402823466e38f)

// ---------------------------------------------------------------------------
// K1: per-token projections Zj, Zi  [B,S,D]
// ---------------------------------------------------------------------------
__global__ __launch_bounds__(256) void proj_kernel(
    const float* __restrict__ Hj, const float* __restrict__ Hi,
    const float* __restrict__ Wpj, const float* __restrict__ Wpi,
    float* __restrict__ Zj, float* __restrict__ Zi)
{
    __shared__ float rowj[H_], rowi[H_];
    const int t = blockIdx.x;           // 0..B*S-1
    const int tid = threadIdx.x;
    const float* hj = Hj + (size_t)t * H_;
    const float* hi = Hi + (size_t)t * H_;
    for (int x = tid; x < H_; x += 256) { rowj[x] = hj[x]; rowi[x] = hi[x]; }
    __syncthreads();

    const int g = tid & 7;              // 8 threads per output
    for (int o = tid >> 3; o < 2 * D_; o += 32) {
        const float* row;
        const float* w;
        if (o < D_) { row = rowj; w = Wpj + o * H_; }
        else        { row = rowi; w = Wpi + (o - D_) * H_; }
        float s = 0.f;
        #pragma unroll 8
        for (int c = 0; c < H_ / 8; ++c) s += row[g + 8 * c] * w[g + 8 * c];
        s += __shfl_down(s, 4, 8);
        s += __shfl_down(s, 2, 8);
        s += __shfl_down(s, 1, 8);
        if (g == 0) {
            if (o < D_) Zj[(size_t)t * D_ + o] = s;
            else        Zi[(size_t)t * D_ + (o - D_)] = s;
        }
    }
}

// ---------------------------------------------------------------------------
// K2: pair logits via f16 MFMA. i-tile 128 (prologue amortized, 1024 blocks
// = 4/CU resident). Feature K-steps: s0=[Zi|0*8], s1=[Zj*Zi|0*8],
// s2=[|Zj-Zi||0*8] built with packed f16 ALU from fragment registers.
// Zj-linear + bias folded into Aterm (fp32 C-in). mfma(W,F): D row=k,col=pair.
// Epilogue reduce over g via LDS scatter (conflict-free) instead of shfl.
// ---------------------------------------------------------------------------
__global__ __launch_bounds__(256) void pair_mfma_kernel(
    const float* __restrict__ Zj, const float* __restrict__ Zi,
    const float* __restrict__ Ws1, const float* __restrict__ Ws2,
    const float* __restrict__ bs1, const float* __restrict__ bs2,
    float* __restrict__ P)
{
    __shared__ float    sZj32[16 * 32];    // f32, cols 24..31 = 0 (for Aterm)
    __shared__ _Float16 sZj16[16 * 32];    // f16, cols 24..31 = 0
    __shared__ _Float16 sZi16[128 * 64];   // 8 granule slots/row; chunk c at c^(r&7), c<4
    __shared__ float    sAterm[16 * 96];   // [j][k]
    __shared__ float    sW1a[96 * 25];
    __shared__ float    sW2[96];
    __shared__ float    sRed[4][64][4];    // per-wave partials [pair][g]

    const int j0 = blockIdx.x * 16, i0 = blockIdx.y * 128, b = blockIdx.z;
    const int tid = threadIdx.x;
    const int lane = tid & 63;
    const int wv = tid >> 6;
    const int q = lane & 15, g = lane >> 4;

    // ---- stage tiles ----
    if (tid < 128) {                    // zj: 16 rows x 8 granules of 4
        int r = tid >> 3, d = tid & 7;
        float4 v = make_float4(0.f, 0.f, 0.f, 0.f);
        if (d < 6) v = *(const float4*)&Zj[((size_t)(b * S_ + j0 + r)) * D_ + 4 * d];
        *(float4*)&sZj32[r * 32 + 4 * d] = v;
        _Float16 h4[4] = {(_Float16)v.x, (_Float16)v.y, (_Float16)v.z, (_Float16)v.w};
        *(ushort4*)&sZj16[r * 32 + 4 * d] = *(const ushort4*)h4;
    }
    for (int t = tid; t < 512; t += 256) {  // zi16: 128 rows x 4 chunks of 8
        int r = t >> 2, c = t & 3;
        int gr = c ^ (r & 7);
        f16x8 o = {0, 0, 0, 0, 0, 0, 0, 0};
        if (c < 3) {
            const float* src = &Zi[((size_t)(b * S_ + i0 + r)) * D_ + 8 * c];
            #pragma unroll
            for (int e = 0; e < 8; ++e) o[e] = (_Float16)src[e];
        }
        *(f16x8*)&sZi16[r * 64 + 8 * gr] = o;
    }
    for (int t = tid; t < 96 * 24; t += 256) {
        int k = t / 24, d = t - k * 24;
        sW1a[k * 25 + d] = Ws1[(size_t)k * 96 + d];
    }
    if (tid < 96) sW2[tid] = Ws2[tid];
    __syncthreads();

    // ---- Aterm[j][k] = bs1[k] + W1a[k,:] . zj[j,:]  (fp32) ----
    for (int o = tid; o < 16 * 96; o += 256) {
        int j = o / 96, k = o - j * 96;
        float acc = bs1[k];
        #pragma unroll
        for (int d = 0; d < 24; ++d) acc += sW1a[k * 25 + d] * sZj32[j * 32 + d];
        sAterm[o] = acc;
    }

    // ---- weight fragments (A-operand, f16): wf[s][nt], lane holds
    // Ws1[nt*16+q][24*(s+1) + 8g .. +7], zeros for g==3 (K-padding) ----
    f16x8 wf[3][6];
    #pragma unroll
    for (int s = 0; s < 3; ++s)
        #pragma unroll
        for (int nt = 0; nt < 6; ++nt) {
            f16x8 t8 = {0, 0, 0, 0, 0, 0, 0, 0};
            if (g < 3) {
                const float* wp = Ws1 + (size_t)(nt * 16 + q) * 96 + 24 * (s + 1) + 8 * g;
                #pragma unroll
                for (int e = 0; e < 8; ++e) t8[e] = (_Float16)wp[e];
            }
            wf[s][nt] = t8;
        }
    const float b2 = bs2[0];
    __syncthreads();

    // w2 in regs (broadcast reads, k = nt*16 + 4g + r)
    f32x4 w2r[6];
    #pragma unroll
    for (int nt = 0; nt < 6; ++nt)
        w2r[nt] = *(const f32x4*)&sW2[nt * 16 + 4 * g];
    const f32x4 zero4 = {0.f, 0.f, 0.f, 0.f};

    // ---- main loop: wave wv owns jj = wv*4+jq; 8 i-subtiles of 16 ----
    for (int jq = 0; jq < 4; ++jq) {
        const int jj = wv * 4 + jq;
        const f16x8 zjh = *(const f16x8*)&sZj16[jj * 32 + 8 * g];  // broadcast
        f32x4 At[6];
        #pragma unroll
        for (int nt = 0; nt < 6; ++nt)
            At[nt] = *(const f32x4*)&sAterm[jj * 96 + nt * 16 + 4 * g];
        float* Prow = &P[((size_t)(b * S_ + j0 + jj)) * S_ + i0];

        for (int ibh = 0; ibh < 2; ++ibh) {
            #pragma unroll
            for (int ib4 = 0; ib4 < 4; ++ib4) {
                const int ii = (ibh * 4 + ib4) * 16 + q;
                const int sw = ii & 7;
                const f16x8 af1 = *(const f16x8*)&sZi16[ii * 64 + 8 * (g ^ sw)];
                const f16x8 a2 = zjh * af1;            // v_pk_mul_f16 x4
                const f16x8 dd = zjh - af1;            // v_pk_add_f16 x4
                const f16x8 a3 = __builtin_elementwise_max(dd, -dd);  // v_pk_max_f16 x4

                f32x4 acc[6];
                #pragma unroll
                for (int nt = 0; nt < 6; ++nt) acc[nt] = At[nt];
                __builtin_amdgcn_s_setprio(1);
                #pragma unroll
                for (int nt = 0; nt < 6; ++nt) {
                    acc[nt] = __builtin_amdgcn_mfma_f32_16x16x32_f16(wf[0][nt], af1, acc[nt], 0, 0, 0);
                    acc[nt] = __builtin_amdgcn_mfma_f32_16x16x32_f16(wf[1][nt], a2,  acc[nt], 0, 0, 0);
                    acc[nt] = __builtin_amdgcn_mfma_f32_16x16x32_f16(wf[2][nt], a3,  acc[nt], 0, 0, 0);
                }
                __builtin_amdgcn_s_setprio(0);

                // per-lane partial: sum over (nt, r) of w2 * relu(h)
                f32x4 lgv = zero4;
                #pragma unroll
                for (int nt = 0; nt < 6; ++nt)
                    lgv += w2r[nt] * __builtin_elementwise_max(acc[nt], zero4);
                sRed[wv][ib4 * 16 + q][g] = (lgv[0] + lgv[1]) + (lgv[2] + lgv[3]);
            }
            // reduce over g via LDS (same wave: DS-pipe in order, waitcnt auto)
            float4 v = *(const float4*)&sRed[wv][lane][0];
            Prow[ibh * 64 + lane] = (v.x + v.y) + (v.z + v.w) + b2;
        }
    }
}

// ---------------------------------------------------------------------------
// K3: row softmax over i (additive key mask); reads fp32 logits, writes bf16
// ---------------------------------------------------------------------------
__global__ __launch_bounds__(256) void softmax_kernel(
    const float* __restrict__ mask, const float* __restrict__ P,
    u16* __restrict__ Pb)
{
    const int r = blockIdx.x;           // b*S + j
    const int b = r / S_;
    const int tid = threadIdx.x;
    const float* row = P + (size_t)r * S_;
    __shared__ float red[4];

    float v[4];
    float mx = -INFINITY;
    #pragma unroll
    for (int c = 0; c < 4; ++c) {
        int i = tid + 256 * c;
        float m = mask[b * S_ + i];
        v[c] = row[i] + (1.0f - m) * NEGF;
        mx = fmaxf(mx, v[c]);
    }
    for (int off = 32; off > 0; off >>= 1) mx = fmaxf(mx, __shfl_xor(mx, off));
    if ((tid & 63) == 0) red[tid >> 6] = mx;
    __syncthreads();
    mx = fmaxf(fmaxf(red[0], red[1]), fmaxf(red[2], red[3]));

    float s = 0.f;
    #pragma unroll
    for (int c = 0; c < 4; ++c) { v[c] = __expf(v[c] - mx); s += v[c]; }
    for (int off = 32; off > 0; off >>= 1) s += __shfl_xor(s, off);
    __syncthreads();
    if ((tid & 63) == 0) red[tid >> 6] = s;
    __syncthreads();
    s = red[0] + red[1] + red[2] + red[3];
    const float inv = 1.0f / s;
    #pragma unroll
    for (int c = 0; c < 4; ++c)
        Pb[(size_t)r * S_ + tid + 256 * c] = (u16)f2bf(v[c] * inv);
}

// ---------------------------------------------------------------------------
// Prep kernels: fp32->bf16 convert, Hi transpose, msg_in build
// ---------------------------------------------------------------------------
__global__ __launch_bounds__(256) void cvt_kernel(
    const float* __restrict__ src, u16* __restrict__ dst, int n4)
{
    int i = blockIdx.x * 256 + threadIdx.x;
    if (i >= n4) return;
    float4 v = ((const float4*)src)[i];
    ushort4 o;
    o.x = (u16)f2bf(v.x); o.y = (u16)f2bf(v.y);
    o.z = (u16)f2bf(v.z); o.w = (u16)f2bf(v.w);
    ((ushort4*)dst)[i] = o;
}

__global__ __launch_bounds__(256) void transpose_hi_kernel(
    const float* __restrict__ Hi, u16* __restrict__ HiT)
{
    __shared__ u16 t[32][33];
    const int i0 = blockIdx.x * 32, h0 = blockIdx.y * 32, b = blockIdx.z;
    const int c = threadIdx.x & 31, r = threadIdx.x >> 5;   // r: 0..7
    #pragma unroll
    for (int rr = r; rr < 32; rr += 8)
        t[rr][c] = (u16)f2bf(Hi[((size_t)(b * S_ + i0 + rr)) * H_ + h0 + c]);
    __syncthreads();
    #pragma unroll
    for (int rr = r; rr < 32; rr += 8)
        HiT[((size_t)(b * H_ + h0 + rr)) * S_ + i0 + c] = t[c][rr];
}

__global__ __launch_bounds__(256) void msgin_kernel(
    const u16* __restrict__ ctx, const float* __restrict__ Hj,
    u16* __restrict__ MSG)
{
    const int idx = blockIdx.x * 256 + threadIdx.x;   // < 2048*96
    const int m = idx / 96, c8 = (idx % 96) * 8;
    bf16x8 c = *(const bf16x8*)&ctx[(size_t)m * H_ + c8];
    float4 h0 = *(const float4*)&Hj[(size_t)m * H_ + c8];
    float4 h1 = *(const float4*)&Hj[(size_t)m * H_ + c8 + 4];
    float hf[8] = {h0.x, h0.y, h0.z, h0.w, h1.x, h1.y, h1.z, h1.w};
    bf16x8 hb, pb;
    #pragma unroll
    for (int e = 0; e < 8; ++e) {
        hb[e] = f2bf(hf[e]);
        pb[e] = f2bf(bf2f(c[e]) * hf[e]);
    }
    u16* row = MSG + (size_t)m * VI_;
    *(bf16x8*)&row[c8]        = c;
    *(bf16x8*)&row[768 + c8]  = hb;
    *(bf16x8*)&row[1536 + c8] = pb;
}

// ---------------------------------------------------------------------------
// bf16 MFMA GEMM: C[2048,768] = A[2048,K] x B[768,K]^T
// 64x64 tile, BK=64, 4 waves (2x2, 32x32 each), dbuf LDS, global_load_lds(16),
// chunk-XOR swizzle (c ^= row&7) pre-applied on global source, applied on read.
// ---------------------------------------------------------------------------
template<int MODE, int K>
__global__ __launch_bounds__(256) void mfma_gemm_kernel(
    const u16* __restrict__ Ag, const u16* __restrict__ Bg,
    const float* __restrict__ bias, const float* __restrict__ alphaPtr,
    void* __restrict__ Outv)
{
    __shared__ u16 As[2][64 * 64];
    __shared__ u16 Bs[2][64 * 64];
    const int tid = threadIdx.x;
    const int lane = tid & 63, wv = tid >> 6;
    const int q = lane & 15, g = lane >> 4;
    const int wr = wv >> 1, wc = wv & 1;
    const int m0 = blockIdx.x * 64, n0 = blockIdx.y * 64;

    const u16* Ab = Ag + (size_t)m0 * K;
    const u16* Bb = (MODE == 0)
        ? Bg + (size_t)(m0 >> 10) * H_ * S_ + (size_t)n0 * K
        : Bg + (size_t)n0 * K;

    int st_r[2], st_gc[2], st_dst[2];
    #pragma unroll
    for (int it = 0; it < 2; ++it) {
        int cidx = (it * 4 + wv) * 64 + lane;
        st_r[it] = cidx >> 3;
        st_gc[it] = (cidx & 7) ^ (st_r[it] & 7);
        st_dst[it] = cidx * 8;
    }

    f32x4 acc[2][2] = {};

    auto stage = [&](int buf, int k0) {
        #pragma unroll
        for (int it = 0; it < 2; ++it) {
            gl_lds16(Ab + (size_t)st_r[it] * K + k0 + st_gc[it] * 8,
                     &As[buf][st_dst[it]]);
            gl_lds16(Bb + (size_t)st_r[it] * K + k0 + st_gc[it] * 8,
                     &Bs[buf][st_dst[it]]);
        }
    };
    auto comp = [&](int buf) {
        #pragma unroll
        for (int ks = 0; ks < 2; ++ks) {
            bf16x8 af[2], bfr[2];
            #pragma unroll
            for (int m = 0; m < 2; ++m) {
                int r = wr * 32 + m * 16 + q;
                int cl = (g + ks * 4) ^ (r & 7);
                af[m] = *(const bf16x8*)&As[buf][r * 64 + cl * 8];
            }
            #pragma unroll
            for (int n = 0; n < 2; ++n) {
                int r = wc * 32 + n * 16 + q;
                int cl = (g + ks * 4) ^ (r & 7);
                bfr[n] = *(const bf16x8*)&Bs[buf][r * 64 + cl * 8];
            }
            #pragma unroll
            for (int m = 0; m < 2; ++m)
                #pragma unroll
                for (int n = 0; n < 2; ++n)
                    acc[m][n] = __builtin_amdgcn_mfma_f32_16x16x32_bf16(
                        af[m], bfr[n], acc[m][n], 0, 0, 0);
        }
    };

    constexpr int NT = K / 64;
    stage(0, 0);
    __syncthreads();
    int cur = 0;
    for (int kt = 0; kt < NT - 1; ++kt) {
        stage(cur ^ 1, (kt + 1) * 64);
        comp(cur);
        __syncthreads();
        cur ^= 1;
    }
    comp(cur);

    const float alpha = (MODE == 2) ? alphaPtr[0] : 0.f;
    u16* O16 = (u16*)Outv;
    float* Of = (float*)Outv;
    #pragma unroll
    for (int m = 0; m < 2; ++m) {
        #pragma unroll
        for (int n = 0; n < 2; ++n) {
            const int col = n0 + wc * 32 + n * 16 + q;
            const float bn = (MODE == 0) ? 0.f : bias[col];
            #pragma unroll
            for (int rg = 0; rg < 4; ++rg) {
                const int row = m0 + wr * 32 + m * 16 + g * 4 + rg;
                float v = acc[m][n][rg];
                if (MODE == 0)      O16[(size_t)row * H_ + col] = (u16)f2bf(v);
                else if (MODE == 1) O16[(size_t)row * H_ + col] = (u16)f2bf(relu_(v + bn));
                else                Of[(size_t)row * H_ + col] = alpha * (v + bn);
            }
        }
    }
}

// ---------------------------------------------------------------------------
extern "C" void kernel_launch(void* const* d_in, const int* in_sizes, int n_in,
                              void* d_out, int out_size, void* d_ws, size_t ws_size,
                              hipStream_t stream)
{
    (void)in_sizes; (void)n_in; (void)out_size; (void)ws_size;
    const float* Hj   = (const float*)d_in[0];
    const float* Hi   = (const float*)d_in[1];
    const float* mask = (const float*)d_in[2];
    const float* Wpj  = (const float*)d_in[3];
    const float* Wpi  = (const float*)d_in[4];
    const float* Ws1  = (const float*)d_in[5];
    const float* bs1  = (const float*)d_in[6];
    const float* Ws2  = (const float*)d_in[7];
    const float* bs2  = (const float*)d_in[8];
    const float* Wv1  = (const float*)d_in[9];
    const float* bv1  = (const float*)d_in[10];
    const float* Wv2  = (const float*)d_in[11];
    const float* bv2  = (const float*)d_in[12];
    const float* alphaPtr = (const float*)d_in[13];
    float* out = (float*)d_out;

    char* w = (char*)d_ws;
    float* Zj   = (float*)(w);                       // 196608 B
    float* Zi   = (float*)(w + 196608);              // 196608 B
    size_t oPlog = 393216;
    size_t oPb   = oPlog + 8388608;    // 8781824
    size_t oHiT  = oPb + 4194304;      // 12976128
    size_t oWv1b = oHiT + 3145728;     // 16121856
    size_t oWv2b = oWv1b + 3538944;    // 19660800
    size_t oCTX  = oWv2b + 1179648;    // 20840448; end ~24 MB
    float* Plog = (float*)(w + oPlog);
    u16* Pb   = (u16*)(w + oPb);
    u16* HiT  = (u16*)(w + oHiT);
    u16* Wv1b = (u16*)(w + oWv1b);
    u16* Wv2b = (u16*)(w + oWv2b);
    u16* CTX  = (u16*)(w + oCTX);
    u16* MSG  = (u16*)(w + oPlog);     // overlay Plog+Pb (dead by then)
    u16* X1   = (u16*)(w + oHiT);      // overlay HiT (dead after gemm0)

    cvt_kernel<<<(H_ * VI_ / 4 + 255) / 256, 256, 0, stream>>>(Wv1, Wv1b, H_ * VI_ / 4);
    cvt_kernel<<<(H_ * OH_ / 4 + 255) / 256, 256, 0, stream>>>(Wv2, Wv2b, H_ * OH_ / 4);
    transpose_hi_kernel<<<dim3(S_ / 32, H_ / 32, B_), 256, 0, stream>>>(Hi, HiT);

    proj_kernel<<<B_ * S_, 256, 0, stream>>>(Hj, Hi, Wpj, Wpi, Zj, Zi);
    pair_mfma_kernel<<<dim3(S_ / 16, S_ / 128, B_), 256, 0, stream>>>(
        Zj, Zi, Ws1, Ws2, bs1, bs2, Plog);
    softmax_kernel<<<B_ * S_, 256, 0, stream>>>(mask, Plog, Pb);

    mfma_gemm_kernel<0, S_><<<dim3(2048 / 64, H_ / 64), 256, 0, stream>>>(
        Pb, HiT, nullptr, nullptr, CTX);
    msgin_kernel<<<(2048 * 96) / 256, 256, 0, stream>>>(CTX, Hj, MSG);
    mfma_gemm_kernel<1, VI_><<<dim3(2048 / 64, OH_ / 64), 256, 0, stream>>>(
        MSG, Wv1b, bv1, nullptr, X1);
    mfma_gemm_kernel<2, OH_><<<dim3(2048 / 64, H_ / 64), 256, 0, stream>>>(
        X1, Wv2b, bv2, alphaPtr, out);
}

// Round 9
// 219.435 us; speedup vs baseline: 1.2731x; 1.0579x over previous
//
#include <hip/hip_runtime.h>
#include <hip/hip_bf16.h>
#include <math.h>

#define B_ 2
#define S_ 1024
#define H_ 768
#define D_ 24
#define HID_ 96
#define OH_ 768
#define VI_ 2304
#define PLANE_E 1572864   // 2048*768 elements per MSG plane

typedef short bf16x8 __attribute__((ext_vector_type(8)));
typedef _Float16 f16x8 __attribute__((ext_vector_type(8)));
typedef float f32x4 __attribute__((ext_vector_type(4)));
typedef unsigned short u16;

static __device__ __forceinline__ float relu_(float x) { return x > 0.f ? x : 0.f; }

static __device__ __forceinline__ short f2bf(float f) {
    __hip_bfloat16 h = __float2bfloat16(f);
    return *reinterpret_cast<short*>(&h);
}

static __device__ __forceinline__ void gl_lds16(const void* g, void* l) {
    __builtin_amdgcn_global_load_lds(
        (const __attribute__((address_space(1))) unsigned int*)g,
        (__attribute__((address_space(3))) unsigned int*)l, 16, 0, 0);
}

#define NEGF (-3.402823466e38f)

// ---------------------------------------------------------------------------
// K0: Ws1 -> f16 MFMA fragment order. wfbuf[(s*6+nt)*64 + lane] = 8 f16:
// lane(q,g): g<3 -> Ws1[nt*16+q][24*(s+1)+8g .. +7], g==3 -> 0 (K padding)
// ---------------------------------------------------------------------------
__global__ __launch_bounds__(256) void ws1frag_kernel(
    const float* __restrict__ Ws1, u16* __restrict__ wfb)
{
    int idx = blockIdx.x * 256 + threadIdx.x;
    if (idx >= 18 * 64) return;
    int frag = idx >> 6, lane = idx & 63;
    int s = frag / 6, nt = frag - s * 6, q = lane & 15, g = lane >> 4;
    u16 out[8] = {0, 0, 0, 0, 0, 0, 0, 0};
    if (g < 3) {
        const float* wp = Ws1 + (size_t)(nt * 16 + q) * 96 + 24 * (s + 1) + 8 * g;
        #pragma unroll
        for (int e = 0; e < 8; ++e) {
            _Float16 h = (_Float16)wp[e];
            out[e] = *reinterpret_cast<u16*>(&h);
        }
    }
    *(ushort4*)&wfb[idx * 8]     = make_ushort4(out[0], out[1], out[2], out[3]);
    *(ushort4*)&wfb[idx * 8 + 4] = make_ushort4(out[4], out[5], out[6], out[7]);
}

// ---------------------------------------------------------------------------
// K1: per-token projections Zj, Zi  [B,S,D]. 4 tokens/block (512 blocks):
// weights re-read 4x less; LDS rows token-transposed so the inner loop is
// one broadcast ds_read_b128 (4 tokens) + 4 FMA per weight element.
// ---------------------------------------------------------------------------
__global__ __launch_bounds__(256) void proj_kernel(
    const float* __restrict__ Hj, const float* __restrict__ Hi,
    const float* __restrict__ Wpj, const float* __restrict__ Wpi,
    float* __restrict__ Zj, float* __restrict__ Zi)
{
    __shared__ float rTj[H_ * 4], rTi[H_ * 4];   // [cc][tok]
    const int t0 = blockIdx.x * 4;
    const int tid = threadIdx.x;
    for (int x = tid; x < 4 * H_; x += 256) {
        int tok = x / H_, cc = x - tok * H_;
        rTj[cc * 4 + tok] = Hj[(size_t)(t0 + tok) * H_ + cc];
        rTi[cc * 4 + tok] = Hi[(size_t)(t0 + tok) * H_ + cc];
    }
    __syncthreads();

    const int g = tid & 7;
    #pragma unroll
    for (int oo = 0; oo < 2; ++oo) {
        const int o = (tid >> 3) + oo * 32;
        if (o >= 48) break;
        const bool isJ = o < 24;
        const float* w = isJ ? (Wpj + (size_t)o * H_) : (Wpi + (size_t)(o - 24) * H_);
        const float* rT = isJ ? rTj : rTi;
        float s0 = 0.f, s1 = 0.f, s2 = 0.f, s3 = 0.f;
        #pragma unroll 8
        for (int c = 0; c < H_ / 8; ++c) {
            float wv = w[g + 8 * c];
            float4 rv = *(const float4*)&rT[(g + 8 * c) * 4];
            s0 += rv.x * wv; s1 += rv.y * wv; s2 += rv.z * wv; s3 += rv.w * wv;
        }
        #pragma unroll
        for (int off = 4; off > 0; off >>= 1) {
            s0 += __shfl_down(s0, off, 8);
            s1 += __shfl_down(s1, off, 8);
            s2 += __shfl_down(s2, off, 8);
            s3 += __shfl_down(s3, off, 8);
        }
        if (g == 0) {
            float* dst = isJ ? Zj : Zi;
            const int oc = isJ ? o : (o - 24);
            dst[(size_t)(t0 + 0) * D_ + oc] = s0;
            dst[(size_t)(t0 + 1) * D_ + oc] = s1;
            dst[(size_t)(t0 + 2) * D_ + oc] = s2;
            dst[(size_t)(t0 + 3) * D_ + oc] = s3;
        }
    }
}

// ---------------------------------------------------------------------------
// K2: pair logits via f16 MFMA, i-tile 128. wf fragments loaded coalesced
// from precomputed wfbuf. Feature K-steps: s0=[Zi|0*8], s1=[Zj*Zi|0*8],
// s2=[|Zj-Zi||0*8] built with packed f16 ALU. Zj-linear + bias folded into
// Aterm (fp32 C-in). mfma(W,F): D row=k, col=pair. g-reduce via LDS scatter.
// ---------------------------------------------------------------------------
__global__ __launch_bounds__(256) void pair_mfma_kernel(
    const float* __restrict__ Zj, const float* __restrict__ Zi,
    const float* __restrict__ Ws1, const u16* __restrict__ wfbuf,
    const float* __restrict__ Ws2,
    const float* __restrict__ bs1, const float* __restrict__ bs2,
    float* __restrict__ P)
{
    __shared__ float    sZj32[16 * 32];    // f32, cols 24..31 = 0 (for Aterm)
    __shared__ _Float16 sZj16[16 * 32];    // f16, cols 24..31 = 0
    __shared__ _Float16 sZi16[128 * 64];   // chunk c at granule c^(r&7), c<4
    __shared__ float    sAterm[16 * 96];   // [j][k]
    __shared__ float    sW1a[96 * 25];
    __shared__ float    sW2[96];
    __shared__ float    sRed[4][64][4];    // per-wave partials [pair][g]

    const int j0 = blockIdx.x * 16, i0 = blockIdx.y * 128, b = blockIdx.z;
    const int tid = threadIdx.x;
    const int lane = tid & 63;
    const int wv = tid >> 6;
    const int q = lane & 15, g = lane >> 4;

    // ---- stage tiles ----
    if (tid < 128) {                    // zj: 16 rows x 8 granules of 4
        int r = tid >> 3, d = tid & 7;
        float4 v = make_float4(0.f, 0.f, 0.f, 0.f);
        if (d < 6) v = *(const float4*)&Zj[((size_t)(b * S_ + j0 + r)) * D_ + 4 * d];
        *(float4*)&sZj32[r * 32 + 4 * d] = v;
        _Float16 h4[4] = {(_Float16)v.x, (_Float16)v.y, (_Float16)v.z, (_Float16)v.w};
        *(ushort4*)&sZj16[r * 32 + 4 * d] = *(const ushort4*)h4;
    }
    for (int t = tid; t < 512; t += 256) {  // zi16: 128 rows x 4 chunks of 8
        int r = t >> 2, c = t & 3;
        int gr = c ^ (r & 7);
        f16x8 o = {0, 0, 0, 0, 0, 0, 0, 0};
        if (c < 3) {
            const float* src = &Zi[((size_t)(b * S_ + i0 + r)) * D_ + 8 * c];
            #pragma unroll
            for (int e = 0; e < 8; ++e) o[e] = (_Float16)src[e];
        }
        *(f16x8*)&sZi16[r * 64 + 8 * gr] = o;
    }
    for (int t = tid; t < 96 * 24; t += 256) {
        int k = t / 24, d = t - k * 24;
        sW1a[k * 25 + d] = Ws1[(size_t)k * 96 + d];
    }
    if (tid < 96) sW2[tid] = Ws2[tid];

    // ---- weight fragments: coalesced 16B loads from wfbuf ----
    f16x8 wf[3][6];
    #pragma unroll
    for (int s = 0; s < 3; ++s)
        #pragma unroll
        for (int nt = 0; nt < 6; ++nt)
            wf[s][nt] = *(const f16x8*)&wfbuf[((s * 6 + nt) * 64 + lane) * 8];
    const float b2 = bs2[0];
    __syncthreads();

    // ---- Aterm[j][k] = bs1[k] + W1a[k,:] . zj[j,:]  (fp32) ----
    for (int o = tid; o < 16 * 96; o += 256) {
        int j = o / 96, k = o - j * 96;
        float acc = bs1[k];
        #pragma unroll
        for (int d = 0; d < 24; ++d) acc += sW1a[k * 25 + d] * sZj32[j * 32 + d];
        sAterm[o] = acc;
    }
    __syncthreads();

    // w2 in regs (broadcast reads, k = nt*16 + 4g + r)
    f32x4 w2r[6];
    #pragma unroll
    for (int nt = 0; nt < 6; ++nt)
        w2r[nt] = *(const f32x4*)&sW2[nt * 16 + 4 * g];
    const f32x4 zero4 = {0.f, 0.f, 0.f, 0.f};

    // ---- main loop: wave wv owns jj = wv*4+jq; 8 i-subtiles of 16 ----
    for (int jq = 0; jq < 4; ++jq) {
        const int jj = wv * 4 + jq;
        const f16x8 zjh = *(const f16x8*)&sZj16[jj * 32 + 8 * g];  // broadcast
        f32x4 At[6];
        #pragma unroll
        for (int nt = 0; nt < 6; ++nt)
            At[nt] = *(const f32x4*)&sAterm[jj * 96 + nt * 16 + 4 * g];
        float* Prow = &P[((size_t)(b * S_ + j0 + jj)) * S_ + i0];

        for (int ibh = 0; ibh < 2; ++ibh) {
            #pragma unroll
            for (int ib4 = 0; ib4 < 4; ++ib4) {
                const int ii = (ibh * 4 + ib4) * 16 + q;
                const int sw = ii & 7;
                const f16x8 af1 = *(const f16x8*)&sZi16[ii * 64 + 8 * (g ^ sw)];
                const f16x8 a2 = zjh * af1;            // v_pk_mul_f16 x4
                const f16x8 dd = zjh - af1;            // v_pk_add_f16 x4
                const f16x8 a3 = __builtin_elementwise_max(dd, -dd);  // v_pk_max_f16 x4

                f32x4 acc[6];
                #pragma unroll
                for (int nt = 0; nt < 6; ++nt) acc[nt] = At[nt];
                __builtin_amdgcn_s_setprio(1);
                #pragma unroll
                for (int nt = 0; nt < 6; ++nt) {
                    acc[nt] = __builtin_amdgcn_mfma_f32_16x16x32_f16(wf[0][nt], af1, acc[nt], 0, 0, 0);
                    acc[nt] = __builtin_amdgcn_mfma_f32_16x16x32_f16(wf[1][nt], a2,  acc[nt], 0, 0, 0);
                    acc[nt] = __builtin_amdgcn_mfma_f32_16x16x32_f16(wf[2][nt], a3,  acc[nt], 0, 0, 0);
                }
                __builtin_amdgcn_s_setprio(0);

                // per-lane partial: sum over (nt, r) of w2 * relu(h)
                f32x4 lgv = zero4;
                #pragma unroll
                for (int nt = 0; nt < 6; ++nt)
                    lgv += w2r[nt] * __builtin_elementwise_max(acc[nt], zero4);
                sRed[wv][ib4 * 16 + q][g] = (lgv[0] + lgv[1]) + (lgv[2] + lgv[3]);
            }
            // reduce over g via LDS (same wave: DS-pipe in order)
            float4 v = *(const float4*)&sRed[wv][lane][0];
            Prow[ibh * 64 + lane] = (v.x + v.y) + (v.z + v.w) + b2;
        }
    }
}

// ---------------------------------------------------------------------------
// K3: row softmax over i (additive key mask); reads fp32 logits, writes bf16
// ---------------------------------------------------------------------------
__global__ __launch_bounds__(256) void softmax_kernel(
    const float* __restrict__ mask, const float* __restrict__ P,
    u16* __restrict__ Pb)
{
    const int r = blockIdx.x;           // b*S + j
    const int b = r / S_;
    const int tid = threadIdx.x;
    const float* row = P + (size_t)r * S_;
    __shared__ float red[4];

    float v[4];
    float mx = -INFINITY;
    #pragma unroll
    for (int c = 0; c < 4; ++c) {
        int i = tid + 256 * c;
        float m = mask[b * S_ + i];
        v[c] = row[i] + (1.0f - m) * NEGF;
        mx = fmaxf(mx, v[c]);
    }
    for (int off = 32; off > 0; off >>= 1) mx = fmaxf(mx, __shfl_xor(mx, off));
    if ((tid & 63) == 0) red[tid >> 6] = mx;
    __syncthreads();
    mx = fmaxf(fmaxf(red[0], red[1]), fmaxf(red[2], red[3]));

    float s = 0.f;
    #pragma unroll
    for (int c = 0; c < 4; ++c) { v[c] = __expf(v[c] - mx); s += v[c]; }
    for (int off = 32; off > 0; off >>= 1) s += __shfl_xor(s, off);
    __syncthreads();
    if ((tid & 63) == 0) red[tid >> 6] = s;
    __syncthreads();
    s = red[0] + red[1] + red[2] + red[3];
    const float inv = 1.0f / s;
    #pragma unroll
    for (int c = 0; c < 4; ++c)
        Pb[(size_t)r * S_ + tid + 256 * c] = (u16)f2bf(v[c] * inv);
}

// ---------------------------------------------------------------------------
// Prep kernels: fp32->bf16 convert, Hi transpose
// ---------------------------------------------------------------------------
__global__ __launch_bounds__(256) void cvt_kernel(
    const float* __restrict__ src, u16* __restrict__ dst, int n4)
{
    int i = blockIdx.x * 256 + threadIdx.x;
    if (i >= n4) return;
    float4 v = ((const float4*)src)[i];
    ushort4 o;
    o.x = (u16)f2bf(v.x); o.y = (u16)f2bf(v.y);
    o.z = (u16)f2bf(v.z); o.w = (u16)f2bf(v.w);
    ((ushort4*)dst)[i] = o;
}

__global__ __launch_bounds__(256) void transpose_hi_kernel(
    const float* __restrict__ Hi, u16* __restrict__ HiT)
{
    __shared__ u16 t[32][33];
    const int i0 = blockIdx.x * 32, h0 = blockIdx.y * 32, b = blockIdx.z;
    const int c = threadIdx.x & 31, r = threadIdx.x >> 5;   // r: 0..7
    #pragma unroll
    for (int rr = r; rr < 32; rr += 8)
        t[rr][c] = (u16)f2bf(Hi[((size_t)(b * S_ + i0 + rr)) * H_ + h0 + c]);
    __syncthreads();
    #pragma unroll
    for (int rr = r; rr < 32; rr += 8)
        HiT[((size_t)(b * H_ + h0 + rr)) * S_ + i0 + c] = t[c][rr];
}

// ---------------------------------------------------------------------------
// bf16 MFMA GEMM: C = A[M,K] x B[N,K]^T. 64x64 tile, BK=64, 4 waves (2x2,
// 32x32 each), dbuf LDS, global_load_lds(16), chunk-XOR swizzle.
// MODE 0: A=Pb (batched rows), B=HiT(+batch); epilogue writes MSG planes
//         {ctx, bf16(Hj), bf16(ctx*Hj)} at PLANE_E stride (bias arg = Hj!).
// MODE 1: A=MSG planes (row stride 768, plane = k0/768), B=Wv1b, relu+bias.
// MODE 2: A=X1, B=Wv2b, alpha*(v+bias), fp32 out.
// ---------------------------------------------------------------------------
template<int MODE, int K>
__global__ __launch_bounds__(256) void mfma_gemm_kernel(
    const u16* __restrict__ Ag, const u16* __restrict__ Bg,
    const float* __restrict__ bias, const float* __restrict__ alphaPtr,
    void* __restrict__ Outv)
{
    __shared__ u16 As[2][64 * 64];
    __shared__ u16 Bs[2][64 * 64];
    const int tid = threadIdx.x;
    const int lane = tid & 63, wv = tid >> 6;
    const int q = lane & 15, g = lane >> 4;
    const int wr = wv >> 1, wc = wv & 1;
    const int m0 = blockIdx.x * 64, n0 = blockIdx.y * 64;

    const u16* Bb = (MODE == 0)
        ? Bg + (size_t)(m0 >> 10) * H_ * S_ + (size_t)n0 * K
        : Bg + (size_t)n0 * K;

    int st_r[2], st_gc[2], st_dst[2];
    #pragma unroll
    for (int it = 0; it < 2; ++it) {
        int cidx = (it * 4 + wv) * 64 + lane;
        st_r[it] = cidx >> 3;
        st_gc[it] = (cidx & 7) ^ (st_r[it] & 7);
        st_dst[it] = cidx * 8;
    }

    f32x4 acc[2][2] = {};

    auto stage = [&](int buf, int k0) {
        const u16* Asrc;
        int kk;
        if (MODE == 1) {
            int pl = k0 / 768;
            kk = k0 - pl * 768;
            Asrc = Ag + (size_t)pl * PLANE_E + (size_t)m0 * 768;
        } else {
            Asrc = Ag + (size_t)m0 * K;
            kk = k0;
        }
        const int AST = (MODE == 1) ? 768 : K;
        #pragma unroll
        for (int it = 0; it < 2; ++it) {
            gl_lds16(Asrc + (size_t)st_r[it] * AST + kk + st_gc[it] * 8,
                     &As[buf][st_dst[it]]);
            gl_lds16(Bb + (size_t)st_r[it] * K + k0 + st_gc[it] * 8,
                     &Bs[buf][st_dst[it]]);
        }
    };
    auto comp = [&](int buf) {
        #pragma unroll
        for (int ks = 0; ks < 2; ++ks) {
            bf16x8 af[2], bfr[2];
            #pragma unroll
            for (int m = 0; m < 2; ++m) {
                int r = wr * 32 + m * 16 + q;
                int cl = (g + ks * 4) ^ (r & 7);
                af[m] = *(const bf16x8*)&As[buf][r * 64 + cl * 8];
            }
            #pragma unroll
            for (int n = 0; n < 2; ++n) {
                int r = wc * 32 + n * 16 + q;
                int cl = (g + ks * 4) ^ (r & 7);
                bfr[n] = *(const bf16x8*)&Bs[buf][r * 64 + cl * 8];
            }
            #pragma unroll
            for (int m = 0; m < 2; ++m)
                #pragma unroll
                for (int n = 0; n < 2; ++n)
                    acc[m][n] = __builtin_amdgcn_mfma_f32_16x16x32_bf16(
                        af[m], bfr[n], acc[m][n], 0, 0, 0);
        }
    };

    constexpr int NT = K / 64;
    stage(0, 0);
    __syncthreads();
    int cur = 0;
    for (int kt = 0; kt < NT - 1; ++kt) {
        stage(cur ^ 1, (kt + 1) * 64);
        comp(cur);
        __syncthreads();
        cur ^= 1;
    }
    comp(cur);

    const float alpha = (MODE == 2) ? alphaPtr[0] : 0.f;
    u16* O16 = (u16*)Outv;
    float* Of = (float*)Outv;
    #pragma unroll
    for (int m = 0; m < 2; ++m) {
        #pragma unroll
        for (int n = 0; n < 2; ++n) {
            const int col = n0 + wc * 32 + n * 16 + q;
            const float bn = (MODE == 0) ? 0.f : bias[col];
            #pragma unroll
            for (int rg = 0; rg < 4; ++rg) {
                const int row = m0 + wr * 32 + m * 16 + g * 4 + rg;
                float v = acc[m][n][rg];
                if (MODE == 0) {
                    // fused msg_in build: bias arg is Hj (fp32)
                    float hj = bias[(size_t)row * H_ + col];
                    O16[(size_t)row * H_ + col]               = (u16)f2bf(v);
                    O16[PLANE_E + (size_t)row * H_ + col]     = (u16)f2bf(hj);
                    O16[2 * PLANE_E + (size_t)row * H_ + col] = (u16)f2bf(v * hj);
                } else if (MODE == 1) {
                    O16[(size_t)row * H_ + col] = (u16)f2bf(relu_(v + bn));
                } else {
                    Of[(size_t)row * H_ + col] = alpha * (v + bn);
                }
            }
        }
    }
}

// ---------------------------------------------------------------------------
extern "C" void kernel_launch(void* const* d_in, const int* in_sizes, int n_in,
                              void* d_out, int out_size, void* d_ws, size_t ws_size,
                              hipStream_t stream)
{
    (void)in_sizes; (void)n_in; (void)out_size; (void)ws_size;
    const float* Hj   = (const float*)d_in[0];
    const float* Hi   = (const float*)d_in[1];
    const float* mask = (const float*)d_in[2];
    const float* Wpj  = (const float*)d_in[3];
    const float* Wpi  = (const float*)d_in[4];
    const float* Ws1  = (const float*)d_in[5];
    const float* bs1  = (const float*)d_in[6];
    const float* Ws2  = (const float*)d_in[7];
    const float* bs2  = (const float*)d_in[8];
    const float* Wv1  = (const float*)d_in[9];
    const float* bv1  = (const float*)d_in[10];
    const float* Wv2  = (const float*)d_in[11];
    const float* bv2  = (const float*)d_in[12];
    const float* alphaPtr = (const float*)d_in[13];
    float* out = (float*)d_out;

    // workspace layout (bytes, high-water 21.91 MB < proven 24 MB):
    // Zj 0 / Zi 196608 / Plog 393216 (8.39MB)
    // MSG planes overlay Plog+: ctx@393216, hb@3538944, pb@6684672 (end 9830400)
    // Pb@9830400 / HiT@14024704 (X1 overlays) / Wv1b@17170432 / Wv2b@20709376
    // wfbuf@21889024
    char* w = (char*)d_ws;
    float* Zj   = (float*)(w);
    float* Zi   = (float*)(w + 196608);
    float* Plog = (float*)(w + 393216);
    u16* MSGp  = (u16*)(w + 393216);          // 3 planes, PLANE_E stride
    u16* Pb    = (u16*)(w + 9830400);
    u16* HiT   = (u16*)(w + 14024704);
    u16* X1    = (u16*)(w + 14024704);        // overlays HiT (dead after gemm0)
    u16* Wv1b  = (u16*)(w + 17170432);
    u16* Wv2b  = (u16*)(w + 20709376);
    u16* wfbuf = (u16*)(w + 21889024);

    // prep (independent)
    ws1frag_kernel<<<5, 256, 0, stream>>>(Ws1, wfbuf);
    cvt_kernel<<<(H_ * VI_ / 4 + 255) / 256, 256, 0, stream>>>(Wv1, Wv1b, H_ * VI_ / 4);
    cvt_kernel<<<(H_ * OH_ / 4 + 255) / 256, 256, 0, stream>>>(Wv2, Wv2b, H_ * OH_ / 4);
    transpose_hi_kernel<<<dim3(S_ / 32, H_ / 32, B_), 256, 0, stream>>>(Hi, HiT);

    proj_kernel<<<B_ * S_ / 4, 256, 0, stream>>>(Hj, Hi, Wpj, Wpi, Zj, Zi);
    pair_mfma_kernel<<<dim3(S_ / 16, S_ / 128, B_), 256, 0, stream>>>(
        Zj, Zi, Ws1, wfbuf, Ws2, bs1, bs2, Plog);
    softmax_kernel<<<B_ * S_, 256, 0, stream>>>(mask, Plog, Pb);

    // ctx GEMM + fused msg_in build (bias arg = Hj)
    mfma_gemm_kernel<0, S_><<<dim3(2048 / 64, H_ / 64), 256, 0, stream>>>(
        Pb, HiT, Hj, nullptr, MSGp);
    // X1 = relu(msg_in @ Wv1^T + b)
    mfma_gemm_kernel<1, VI_><<<dim3(2048 / 64, OH_ / 64), 256, 0, stream>>>(
        MSGp, Wv1b, bv1, nullptr, X1);
    // out = alpha*(X1 @ Wv2^T + b)
    mfma_gemm_kernel<2, OH_><<<dim3(2048 / 64, H_ / 64), 256, 0, stream>>>(
        X1, Wv2b, bv2, alphaPtr, out);
}